// Round 6
// baseline (162.520 us; speedup 1.0000x reference)
//
#include <hip/hip_runtime.h>
#include <hip/hip_bf16.h>

typedef __bf16 bf16;
typedef __bf16 bf16x4 __attribute__((ext_vector_type(4)));
typedef __bf16 bf16x8 __attribute__((ext_vector_type(8)));
typedef float f32x4 __attribute__((ext_vector_type(4)));

#define DIM 768
#define HW 1024          // 32*32
#define BATCH 16
#define M_TOTAL (BATCH * HW)   // 16384
#define NKT 24                 // K-tiles of 32

#define AS1 __attribute__((address_space(1)))
#define AS3 __attribute__((address_space(3)))

// ======================== k-permutation convention =========================
// All bf16 [.][768] activation buffers and Wb[768][768] store the k (channel)
// dimension permuted within each 32-group: physical position p = 8g+j holds
// logical k = 4g+j (j<4) or 16+4g+(j-4) (j>=4). mfma_f32_16x16x32_bf16
// fragments are then 16B-contiguous -> single ds_read_b128 per fragment.
// k2pos(kk) = (((kk&15)>>2)<<3) + (kk&3) + ((kk>>4)<<2).

// ---------------- weight convert: f32 -> bf16, k-permuted ----------------
__global__ void wcvt3_kernel(const float4* __restrict__ w1, const float4* __restrict__ w2,
                             const float4* __restrict__ w3,
                             bf16x8* __restrict__ o1, bf16x8* __restrict__ o2,
                             bf16x8* __restrict__ o3) {
    const int b = blockIdx.x;              // 0..863
    const int which = b / 288;
    const int i = (b % 288) * 256 + threadIdx.x;   // output 16B blocks
    const float4* w = which == 0 ? w1 : which == 1 ? w2 : w3;
    bf16x8* o = which == 0 ? o1 : which == 1 ? o2 : o3;
    const int row = i / 96, br = i % 96;
    const int q = br >> 2, g = br & 3;
    float4 lo = w[row * 192 + q * 8 + g];
    float4 hi = w[row * 192 + q * 8 + g + 4];
    bf16x8 r = { (bf16)lo.x, (bf16)lo.y, (bf16)lo.z, (bf16)lo.w,
                 (bf16)hi.x, (bf16)hi.y, (bf16)hi.z, (bf16)hi.w };
    o[row * 96 + br] = r;
}

// ------- transpose + convert: x[16][768][1024] f32 -> xb[16384][768p] bf16 -------
__global__ void transpose_cvt_kernel(const float* __restrict__ x, bf16* __restrict__ xb) {
    __shared__ float tile[32][33];
    const int b = blockIdx.z;
    const int hw0 = blockIdx.x * 32;
    const int c0 = blockIdx.y * 32;
    const int tx = threadIdx.x, ty = threadIdx.y;  // 32 x 8

    const float* src = x + ((size_t)b * DIM + c0) * HW + hw0;
#pragma unroll
    for (int j = 0; j < 4; j++)
        tile[ty + 8 * j][tx] = src[(size_t)(ty + 8 * j) * HW + tx];
    __syncthreads();
    const int ptx = (((tx & 15) >> 2) << 3) + (tx & 3) + ((tx >> 4) << 2);  // k2pos
    bf16* dst = xb + ((size_t)b * HW + hw0) * DIM + c0;
#pragma unroll
    for (int j = 0; j < 4; j++)
        dst[(size_t)(ty + 8 * j) * DIM + ptx] = (bf16)tile[tx][ty + 8 * j];
}

// ============ fused GEMM: C[M][768] = A[M][768] * W^T (+bias) [+LN+GELU] ============
// BM=64, BN=768 (full row -> LN fusable), BK=32, 8 waves (2 wm x 4 wn),
// wave tile 32x192, grid = 256 = 1 block/CU.
// One barrier + one counted vmcnt per K-tile; B staged 1 tile ahead (dbuf),
// A staged 2 tiles ahead in 64-k pairs (rides barrier in flight, vmcnt(1)).
// MODE 0: LN+GELU epilogue, bf16 k-permuted out. MODE 1: bias only, f32 NCHW out.
template <int MODE>
__global__ __launch_bounds__(512, 2) void gemm_kernel(
    const bf16* __restrict__ A,    // [M][768] k-permuted
    const bf16* __restrict__ Bw,   // [768][768] rows linear, cols k-permuted
    const float* __restrict__ bias,
    const float* __restrict__ gamma,
    const float* __restrict__ beta,
    void* __restrict__ out)
{
    __shared__ bf16 ldsB[2][DIM][32];   // 96 KiB, dbuf = kt&1
    __shared__ bf16 ldsA[2][64][64];    // 16 KiB, dbuf = pair&1 (pair = kt>>1)
    __shared__ float lnred[64][4][2];   // 2 KiB LN partials

    const int t = threadIdx.x;
    const int lane = t & 63;
    const int wave = t >> 6;
    const int wm = wave >> 2, wn = wave & 3;

    const int bid = blockIdx.x;                 // 256 blocks
    const int swz = (bid & 7) * 32 + (bid >> 3);
    const int m0 = swz * 64;

    const int fr = lane & 15, fq = lane >> 4;

    f32x4 acc[2][12] = {};

    // staging lane mapping
    const int sBr = t >> 2, sBb = t & 3;   // B: 128 rows/chunk, 4 blocks of 16B
    const int sAr = t >> 3, sAb = t & 7;   // A: 64 rows, 8 blocks of 16B
    const int swzBw = (sBr & 3) ^ ((sBr >> 2) & 3);

    auto stageB = [&](int kt, int chunk) {     // 1 global_load_lds / thread
        const int d = kt & 1;
        const int r = chunk * 128 + sBr;
        __builtin_amdgcn_global_load_lds(
            (const AS1 void*)(Bw + (size_t)r * DIM + kt * 32 + ((sBb ^ swzBw) << 3)),
            (AS3 void*)&ldsB[d][r][sBb * 8], 16, 0, 0);
    };
    auto stageA = [&](int pair) {              // 1 global_load_lds / thread
        const int d = pair & 1;
        __builtin_amdgcn_global_load_lds(
            (const AS1 void*)(A + (size_t)(m0 + sAr) * DIM + pair * 64 + ((sAb ^ (sAr & 7)) << 3)),
            (AS3 void*)&ldsA[d][sAr][sAb * 8], 16, 0, 0);
    };

    bf16x8 af[2], bfr[6];
    auto ldA = [&](int kt) {                   // 2 ds_read_b128
        const int d = (kt >> 1) & 1, kb = (kt & 1) * 4;
#pragma unroll
        for (int mi = 0; mi < 2; mi++) {
            const int R = wm * 32 + mi * 16 + fr;
            af[mi] = *(const bf16x8*)(&ldsA[d][R][0] + (((kb + fq) ^ (R & 7)) << 3));
        }
    };
    auto ldB6 = [&](int kt, int nh) {          // 6 ds_read_b128
        const int d = kt & 1;
#pragma unroll
        for (int j = 0; j < 6; j++) {
            const int R = wn * 192 + (nh * 6 + j) * 16 + fr;
            bfr[j] = *(const bf16x8*)(&ldsB[d][R][0] +
                       ((fq ^ ((R & 3) ^ ((R >> 2) & 3))) << 3));
        }
    };
    auto MM = [&](int nh) {                    // 12 MFMA, setprio-wrapped
        __builtin_amdgcn_s_setprio(1);
#pragma unroll
        for (int mi = 0; mi < 2; mi++)
#pragma unroll
            for (int j = 0; j < 6; j++)
                acc[mi][nh * 6 + j] = __builtin_amdgcn_mfma_f32_16x16x32_bf16(
                    af[mi], bfr[j], acc[mi][nh * 6 + j], 0, 0, 0);
        __builtin_amdgcn_s_setprio(0);
    };

    // ---------------- prologue: tile 0 fully staged ----------------
#pragma unroll
    for (int c = 0; c < 6; c++) stageB(0, c);
    stageA(0);
    asm volatile("s_waitcnt vmcnt(0)" ::: "memory");
    __builtin_amdgcn_s_barrier();

    // main loop, 2-unrolled for vmcnt parity; kt = 0..21
    for (int kt2 = 0; kt2 < NKT - 2; kt2 += 2) {
        // even kt
        ldA(kt2); ldB6(kt2, 0);
        stageB(kt2 + 1, 0); stageB(kt2 + 1, 1); stageB(kt2 + 1, 2);
        MM(0);
        ldB6(kt2, 1);
        stageB(kt2 + 1, 3); stageB(kt2 + 1, 4); stageB(kt2 + 1, 5);
        stageA((kt2 + 2) >> 1);                 // issued LAST -> rides vmcnt(1)
        MM(1);
        asm volatile("s_waitcnt vmcnt(1)" ::: "memory");  // B(kt+1) resident, A flies
        __builtin_amdgcn_s_barrier();
        // odd kt
        const int ko = kt2 + 1;
        ldA(ko); ldB6(ko, 0);
        stageB(ko + 1, 0); stageB(ko + 1, 1); stageB(ko + 1, 2);
        MM(0);
        ldB6(ko, 1);
        stageB(ko + 1, 3); stageB(ko + 1, 4); stageB(ko + 1, 5);
        MM(1);
        asm volatile("s_waitcnt vmcnt(0)" ::: "memory");  // B(kt+1) + A-pair resident
        __builtin_amdgcn_s_barrier();
    }
    {   // kt = 22: stage B(23) only (no A left)
        ldA(22); ldB6(22, 0);
        stageB(23, 0); stageB(23, 1); stageB(23, 2);
        MM(0);
        ldB6(22, 1);
        stageB(23, 3); stageB(23, 4); stageB(23, 5);
        MM(1);
        asm volatile("s_waitcnt vmcnt(0)" ::: "memory");
        __builtin_amdgcn_s_barrier();
        // kt = 23: compute only
        ldA(23); ldB6(23, 0);
        MM(0);
        ldB6(23, 1);
        MM(1);
    }

    // ---------------- epilogue ----------------
    float bv[12];
#pragma unroll
    for (int j = 0; j < 12; j++) bv[j] = bias[wn * 192 + j * 16 + fr];

    if (MODE == 0) {
        float gv[12], bev[12];
#pragma unroll
        for (int j = 0; j < 12; j++) {
            const int col = wn * 192 + j * 16 + fr;
            gv[j] = gamma[col]; bev[j] = beta[col];
        }
        // per-row partial sums over this wave's 192 cols
#pragma unroll
        for (int mi = 0; mi < 2; mi++)
#pragma unroll
            for (int r = 0; r < 4; r++) {
                float s = 0.f, ss = 0.f;
#pragma unroll
                for (int j = 0; j < 12; j++) {
                    const float v = acc[mi][j][r] + bv[j];
                    s += v; ss += v * v;
                }
#pragma unroll
                for (int o = 1; o < 16; o <<= 1) {
                    s += __shfl_xor(s, o); ss += __shfl_xor(ss, o);
                }
                if (fr == 0) {
                    const int row = wm * 32 + mi * 16 + fq * 4 + r;
                    lnred[row][wn][0] = s; lnred[row][wn][1] = ss;
                }
            }
        __builtin_amdgcn_s_barrier();
        bf16* o = (bf16*)out;
#pragma unroll
        for (int mi = 0; mi < 2; mi++)
#pragma unroll
            for (int r = 0; r < 4; r++) {
                const int row = wm * 32 + mi * 16 + fq * 4 + r;
                const float s  = lnred[row][0][0] + lnred[row][1][0] + lnred[row][2][0] + lnred[row][3][0];
                const float ss = lnred[row][0][1] + lnred[row][1][1] + lnred[row][2][1] + lnred[row][3][1];
                const float mu = s * (1.f / DIM);
                const float var = ss * (1.f / DIM) - mu * mu;
                const float rstd = rsqrtf(var + 1e-6f);
#pragma unroll
                for (int j = 0; j < 12; j++) {
                    float y = (acc[mi][j][r] + bv[j] - mu) * rstd * gv[j] + bev[j];
                    y = 0.5f * y * (1.f + erff(y * 0.70710678118f));
                    const int pcol = wn * 192 + ((j >> 1) << 5) + ((fr >> 2) << 3)
                                   + (fr & 3) + ((j & 1) << 2);   // k2pos
                    o[(size_t)(m0 + row) * DIM + pcol] = (bf16)y;
                }
            }
    } else {
        float* o = (float*)out;
#pragma unroll
        for (int mi = 0; mi < 2; mi++) {
            const int nb = m0 + wm * 32 + mi * 16 + fq * 4;
            const int bI = nb >> 10, hw = nb & 1023;
#pragma unroll
            for (int j = 0; j < 12; j++) {
                const int col = wn * 192 + j * 16 + fr;
                f32x4 v = acc[mi][j] + bv[j];
                *(f32x4*)(o + ((size_t)bI * DIM + col) * HW + hw) = v;
            }
        }
    }
}

extern "C" void kernel_launch(void* const* d_in, const int* in_sizes, int n_in,
                              void* d_out, int out_size, void* d_ws, size_t ws_size,
                              hipStream_t stream) {
    const float* x   = (const float*)d_in[0];
    const float* W1  = (const float*)d_in[1];
    const float* b1  = (const float*)d_in[2];
    const float* g1  = (const float*)d_in[3];
    const float* be1 = (const float*)d_in[4];
    const float* W2  = (const float*)d_in[5];
    const float* b2  = (const float*)d_in[6];
    const float* g2  = (const float*)d_in[7];
    const float* be2 = (const float*)d_in[8];
    const float* W3  = (const float*)d_in[9];
    const float* b3  = (const float*)d_in[10];
    float* out = (float*)d_out;

    bf16* Wb1  = (bf16*)d_ws;
    bf16* Wb2  = Wb1 + (size_t)DIM * DIM;
    bf16* Wb3  = Wb2 + (size_t)DIM * DIM;
    bf16* buf0 = Wb3 + (size_t)DIM * DIM;          // 16384*768 bf16
    bf16* buf1 = buf0 + (size_t)M_TOTAL * DIM;

    // weights -> bf16 k-permuted
    wcvt3_kernel<<<864, 256, 0, stream>>>((const float4*)W1, (const float4*)W2, (const float4*)W3,
                                          (bf16x8*)Wb1, (bf16x8*)Wb2, (bf16x8*)Wb3);

    // x NCHW -> [n][c] bf16 k-permuted
    transpose_cvt_kernel<<<dim3(32, 24, 16), dim3(32, 8), 0, stream>>>(x, buf0);

    // layer 1+LN+GELU, layer 2+LN+GELU, layer 3 -> NCHW f32
    gemm_kernel<0><<<256, 512, 0, stream>>>(buf0, Wb1, b1, g1, be1, buf1);
    gemm_kernel<0><<<256, 512, 0, stream>>>(buf1, Wb2, b2, g2, be2, buf0);
    gemm_kernel<1><<<256, 512, 0, stream>>>(buf0, Wb3, b3, b3, b3, out);
}